// Round 3
// baseline (7430.664 us; speedup 1.0000x reference)
//
#include <hip/hip_runtime.h>
#include <stdint.h>

typedef _Float16 f16;
typedef _Float16 f16x8 __attribute__((ext_vector_type(8)));
typedef float f32x4 __attribute__((ext_vector_type(4)));

// ---------- LLC-coherent (L2-bypass) loads: system-scope sc0 sc1 ----------
// Reads execute at the Infinity Cache (coherence point), immune to stale per-XCD L2
// lines, and leave the L2's read-only working set (weights, encK/V) untouched.
// NOTE: asm operands must be native vector types (f32x4), NOT HIP float4 (class type).
__device__ __forceinline__ float llc_loadf(const float* p) {
  float r;
  asm volatile("global_load_dword %0, %1, off sc0 sc1\n\t"
               "s_waitcnt vmcnt(0)"
               : "=v"(r) : "v"(p) : "memory");
  return r;
}

__device__ __forceinline__ void llc_load4x5(const f32x4* p0, const f32x4* p1,
                                            const f32x4* p2, const f32x4* p3,
                                            const f32x4* p4, f32x4& a, f32x4& b,
                                            f32x4& c, f32x4& d, f32x4& e) {
  asm volatile("global_load_dwordx4 %0, %5, off sc0 sc1\n\t"
               "global_load_dwordx4 %1, %6, off sc0 sc1\n\t"
               "global_load_dwordx4 %2, %7, off sc0 sc1\n\t"
               "global_load_dwordx4 %3, %8, off sc0 sc1\n\t"
               "global_load_dwordx4 %4, %9, off sc0 sc1\n\t"
               "s_waitcnt vmcnt(0)"
               : "=&v"(a), "=&v"(b), "=&v"(c), "=&v"(d), "=&v"(e)
               : "v"(p0), "v"(p1), "v"(p2), "v"(p3), "v"(p4)
               : "memory");
}

// ============================ K0: prep / pack / gather ============================
__global__ __launch_bounds__(256) void k0_prep(
    const float* __restrict__ Wih1, const float* __restrict__ Whh1,
    const float* __restrict__ bih1, const float* __restrict__ bhh1,
    const float* __restrict__ Wih2, const float* __restrict__ Whh2,
    const float* __restrict__ bih2, const float* __restrict__ bhh2,
    const float* __restrict__ Wout, const float* __restrict__ emb,
    const int* __restrict__ text,
    float* __restrict__ Wpack, float* __restrict__ Wpack2,
    float* __restrict__ b1s, float* __restrict__ b2s,
    f16* __restrict__ Wst16, f16* __restrict__ Wout16, f16* __restrict__ A1)
{
  const long long TOT = 14158336LL;
  for (long long i = (long long)blockIdx.x * 256 + threadIdx.x; i < TOT;
       i += (long long)gridDim.x * 256) {
    long long x = i;
    if (x < 1310720) {  // Wpack[j][k]: k<128 -> Wih1 ctx cols, else Whh1
      int j = (int)(x / 640), k = (int)(x % 640);
      Wpack[x] = (k < 128) ? Wih1[(long long)j * 640 + 512 + k]
                           : Whh1[(long long)j * 512 + (k - 128)];
      continue;
    }
    x -= 1310720;
    if (x < 327680) {  // Wpack2[j2][k]: k<512 -> Wih2, else Whh2
      int j = (int)(x / 640), k = (int)(x % 640);
      Wpack2[x] = (k < 512) ? Wih2[(long long)j * 512 + k]
                            : Whh2[(long long)j * 128 + (k - 512)];
      continue;
    }
    x -= 327680;
    if (x < 1048576) {  // Wst16[j][k] = fp16(Wih1[j][k]) static cols
      int j = (int)(x >> 9), k = (int)(x & 511);
      Wst16[x] = (f16)Wih1[(long long)j * 640 + k];
      continue;
    }
    x -= 1048576;
    if (x < 8192000) { Wout16[x] = (f16)Wout[x]; continue; }
    x -= 8192000;
    if (x < 2560) {
      if (x < 2048) b1s[x] = bih1[x] + bhh1[x];
      else b2s[x - 2048] = bih2[x - 2048] + bhh2[x - 2048];
      continue;
    }
    x -= 2560;
    {  // A1[m][k] = fp16(embedding[text[n][s]][k]), m = s*64+n, pad rows -> token 0 (zero row)
      int m = (int)(x >> 9), k = (int)(x & 511);
      int tok = (m < 6336) ? text[(m & 63) * 100 + (m >> 6)] : 0;
      A1[x] = (f16)emb[(long long)tok * 512 + k];
    }
  }
}

// ============================ K1/K3: fp16 MFMA GEMM ============================
// C[m][n] = sum_k A[m][k]*B[n][k] + bias[n];  M=6400(pad, write m<6336), tiles 128x128, BK=64
// EPI==1: K1 -> Gst fp16 [s][j][nb];  EPI==2: K3 -> pred f32 [nb][s][j]
template <int EPI>
__global__ __launch_bounds__(256) void gemm_f16(
    const f16* __restrict__ A, const f16* __restrict__ B,
    const float* __restrict__ bias, float* __restrict__ oF, f16* __restrict__ oH, int Kdim)
{
  __shared__ __align__(16) f16 As[128][72];  // pad 64->72: 2-way max bank alias (free)
  __shared__ __align__(16) f16 Bs[128][72];
  const int tid = threadIdx.x, lane = tid & 63, wv = tid >> 6;
  const int m0 = blockIdx.y << 7, n0 = blockIdx.x << 7;
  f32x4 acc[2][8];
#pragma unroll
  for (int i = 0; i < 2; i++)
#pragma unroll
    for (int t = 0; t < 8; t++) acc[i][t] = (f32x4){0.f, 0.f, 0.f, 0.f};
  for (int kt = 0; kt < Kdim; kt += 64) {
    __syncthreads();
#pragma unroll
    for (int i = tid; i < 1024; i += 256) {  // 128 rows x 8 chunks of 8 f16
      int r = i >> 3, c = (i & 7) << 3;
      *(f16x8*)&As[r][c] = *(const f16x8*)&A[(long long)(m0 + r) * Kdim + kt + c];
      *(f16x8*)&Bs[r][c] = *(const f16x8*)&B[(long long)(n0 + r) * Kdim + kt + c];
    }
    __syncthreads();
#pragma unroll
    for (int ks = 0; ks < 2; ks++) {
      const int kc = (ks << 5) + ((lane >> 4) << 3);
      f16x8 a0 = *(const f16x8*)&As[(wv << 5) + (lane & 15)][kc];
      f16x8 a1 = *(const f16x8*)&As[(wv << 5) + 16 + (lane & 15)][kc];
#pragma unroll
      for (int nt = 0; nt < 8; nt++) {
        f16x8 b = *(const f16x8*)&Bs[(nt << 4) + (lane & 15)][kc];
        acc[0][nt] = __builtin_amdgcn_mfma_f32_16x16x32_f16(a0, b, acc[0][nt], 0, 0, 0);
        acc[1][nt] = __builtin_amdgcn_mfma_f32_16x16x32_f16(a1, b, acc[1][nt], 0, 0, 0);
      }
    }
  }
  const int rb = m0 + (wv << 5) + ((lane >> 4) << 2);  // D row = quad*4+r
  const int cb = lane & 15;                            // D col = lane&15
#pragma unroll
  for (int i = 0; i < 2; i++)
#pragma unroll
    for (int nt = 0; nt < 8; nt++) {
      const int j = n0 + (nt << 4) + cb;
#pragma unroll
      for (int r = 0; r < 4; r++) {
        int m = rb + (i << 4) + r;
        if (m < 6336) {
          int s = m >> 6, n = m & 63;
          float dv = acc[i][nt][r] + bias[j];
          if (EPI == 1) oH[((long long)s * 2048 + j) * 64 + n] = (f16)dv;
          else          oF[(long long)n * 3168000 + (long long)s * 32000 + j] = dv;
        }
      }
    }
}

// ============================ K2: persistent recurrent kernel ============================
// Barrier protocol: producers use normal stores + a RELEASE-only agent fence
// (buffer_wbl2 writeback, NO buffer_inv). Consumers read the ~200 KB of mutable
// cross-wg state via sc0sc1 LLC loads. => zero L2 invalidates; Wpack/Wpack2/encK/encV
// stay L2-resident across all 99 steps.
__device__ __forceinline__ void gridbar(int* bar, int w, int tid, int& ep) {
  __syncthreads();
  if (tid == 0) {
    const int e = ++ep;
    __builtin_amdgcn_fence(__ATOMIC_RELEASE, "agent");  // writeback dirty L2 (keeps clean lines!)
    const int g = w & 7;
    int a = atomicAdd(bar + (g << 8), 1);      // 8 counters, 1 KB apart, 32 wgs each
    if (a == e * 32 - 1) {
      int r = atomicAdd(bar + 2048, 1);        // root
      if (r == e * 8 - 1) {
#pragma unroll
        for (int f = 0; f < 8; f++)
          __hip_atomic_store(bar + 2304 + (f << 8), e, __ATOMIC_RELAXED,
                             __HIP_MEMORY_SCOPE_AGENT);
      }
    }
    while (__hip_atomic_load(bar + 2304 + (g << 8), __ATOMIC_RELAXED,
                             __HIP_MEMORY_SCOPE_AGENT) < e)
      __builtin_amdgcn_s_sleep(2);
    // no acquire fence: all cross-wg mutable reads bypass L2 (sc0 sc1)
  }
  __syncthreads();
}

__global__ __launch_bounds__(512) void k2_recur(
    const f16* __restrict__ Gst, const float* __restrict__ Wpack,
    const float* __restrict__ Wpack2, const float* __restrict__ b2s,
    const float* __restrict__ encK, const float* __restrict__ encV,
    const int* __restrict__ lens,
    float* __restrict__ XC, float* __restrict__ X1b, float* __restrict__ X2b,
    float* __restrict__ H2R,
    unsigned long long* __restrict__ MBV, int* __restrict__ MBF, int* __restrict__ BAR,
    f16* __restrict__ h2c, float* __restrict__ attn)
{
  __shared__ __align__(16) float XS[10240];  // 40 KB: X staging chunks / gate exchange / softmax scratch
  const int w = blockIdx.x, tid = threadIdx.x;
  const int lane = tid & 63, wvv = tid >> 6;
  int ep = 0;
  float c1v = 0.f, c2v = 0.f;  // LSTM cell state: wg-private -> registers

  for (int s = 0; s < 99; s++) {
    const int p = s & 1;
    // ---------- phase A: LSTM1 (all 256 wgs; wg owns d-pair {2w,2w+1}, wave = one gate row) ----------
    {
      const int g = wvv >> 1, d = 2 * w + (wvv & 1);
      // readfirstlane: make the weight-row index formally wave-uniform so wc[k]
      // selects to the scalar pipe instead of 64-lane same-address vector loads.
      const int j = __builtin_amdgcn_readfirstlane((g << 9) + d);
      float acc = (float)Gst[((long long)s * 2048 + j) * 64 + lane];
      const float* wrow = Wpack + (long long)j * 640;
      const f32x4* xc4 = (const f32x4*)XC;
      const f32x4* x1p4 = (const f32x4*)(X1b + p * 32768);
      for (int c = 0; c < 4; c++) {  // stage 160 k-rows at a time: [XC(128) | h1(512)]
        __syncthreads();
        {
          const f32x4* ps[5];
#pragma unroll
          for (int u = 0; u < 5; u++) {
            int i = tid + (u << 9);
            int fidx = 2560 * c + i;
            int r = fidx >> 4;
            ps[u] = (r < 128) ? (xc4 + fidx) : (x1p4 + (fidx - 2048));
          }
          f32x4 v0, v1, v2, v3, v4;
          llc_load4x5(ps[0], ps[1], ps[2], ps[3], ps[4], v0, v1, v2, v3, v4);
          ((f32x4*)XS)[tid]          = v0;
          ((f32x4*)XS)[tid + 512]    = v1;
          ((f32x4*)XS)[tid + 1024]   = v2;
          ((f32x4*)XS)[tid + 1536]   = v3;
          ((f32x4*)XS)[tid + 2048]   = v4;
        }
        __syncthreads();
        const float* wc = wrow + 160 * c;
#pragma unroll 8
        for (int k = 0; k < 160; k++) acc = fmaf(XS[(k << 6) + lane], wc[k], acc);
      }
      __syncthreads();
      XS[(wvv << 6) + lane] = acc;  // gate exchange
      __syncthreads();
      if (tid < 128) {
        const int dd = tid >> 6, n = tid & 63, dl = 2 * w + dd;
        float gi = XS[(dd << 6) + n];
        float gf = XS[((2 + dd) << 6) + n];
        float gg = XS[((4 + dd) << 6) + n];
        float go = XS[((6 + dd) << 6) + n];
        float si = 1.f / (1.f + expf(-gi));
        float sf = 1.f / (1.f + expf(-gf));
        float so = 1.f / (1.f + expf(-go));
        float cn = sf * c1v + si * tanhf(gg);
        float h = so * tanhf(cn);
        c1v = cn;
        (X1b + (p ^ 1) * 32768)[(dl << 6) + n] = h;
      }
    }
    gridbar(BAR, w, tid, ep);
    // ---------- phase B: LSTM2 (wgs 0..63) + side tasks (wgs 64..127) ----------
    if (w < 64) {
      const int g = wvv >> 1, d2 = 2 * w + (wvv & 1);
      const int j2 = __builtin_amdgcn_readfirstlane((g << 7) + d2);
      float acc = b2s[j2];
      const float* wrow = Wpack2 + (long long)j2 * 640;
      const f32x4* x1n4 = (const f32x4*)(X1b + (p ^ 1) * 32768);
      const f32x4* x2p4 = (const f32x4*)(X2b + p * 8192);
      for (int c = 0; c < 4; c++) {  // k-rows: [h1new(512) | h2old(128)]
        __syncthreads();
        {
          const f32x4* ps[5];
#pragma unroll
          for (int u = 0; u < 5; u++) {
            int i = tid + (u << 9);
            int fidx = 2560 * c + i;
            int r = fidx >> 4;
            ps[u] = (r < 512) ? (x1n4 + fidx) : (x2p4 + (fidx - 8192));
          }
          f32x4 v0, v1, v2, v3, v4;
          llc_load4x5(ps[0], ps[1], ps[2], ps[3], ps[4], v0, v1, v2, v3, v4);
          ((f32x4*)XS)[tid]          = v0;
          ((f32x4*)XS)[tid + 512]    = v1;
          ((f32x4*)XS)[tid + 1024]   = v2;
          ((f32x4*)XS)[tid + 1536]   = v3;
          ((f32x4*)XS)[tid + 2048]   = v4;
        }
        __syncthreads();
        const float* wc = wrow + 160 * c;
#pragma unroll 8
        for (int k = 0; k < 160; k++) acc = fmaf(XS[(k << 6) + lane], wc[k], acc);
      }
      __syncthreads();
      XS[(wvv << 6) + lane] = acc;
      __syncthreads();
      if (tid < 128) {
        const int dd = tid >> 6, n = tid & 63, dl = 2 * w + dd;
        float gi = XS[(dd << 6) + n];
        float gf = XS[((2 + dd) << 6) + n];
        float gg = XS[((4 + dd) << 6) + n];
        float go = XS[((6 + dd) << 6) + n];
        float si = 1.f / (1.f + expf(-gi));
        float sf = 1.f / (1.f + expf(-gf));
        float so = 1.f / (1.f + expf(-go));
        float cn = sf * c2v + si * tanhf(gg);
        float h = so * tanhf(cn);
        c2v = cn;
        (X2b + (p ^ 1) * 8192)[(dl << 6) + n] = h;
        H2R[(n << 7) + dl] = h;
        h2c[((long long)(s * 64 + n)) * 256 + dl] = (f16)h;  // K3 A-matrix h2 part
      }
    } else if (w < 128) {
      // finalize ctx(s-1) into K3 A-matrix, then zero XC for this step's accumulation
      const int n = w - 64;
      if (tid < 128) {
        float val = llc_loadf(&XC[(tid << 6) + n]);
        if (s > 0) h2c[((long long)((s - 1) * 64 + n)) * 256 + 128 + tid] = (f16)val;
        XC[(tid << 6) + n] = 0.f;
      }
    }
    gridbar(BAR, w, tid, ep);
    // ---------- phase C: attention (4 wgs per batch, t-slice of 128 each) ----------
    {
      const int q = w >> 6, n = w & 63, t0 = q << 7;
      const int len = lens[n];
      if (tid < 128) XS[tid] = llc_loadf(&H2R[(n << 7) + tid]);  // h2
      __syncthreads();
      {  // energy partials: thread = (t_local, k-quarter)
        const int tl = tid >> 2, kq = tid & 3;
        const float* Kr = encK + ((long long)n * 512 + t0 + tl) * 128 + (kq << 5);
        float pp = 0.f;
#pragma unroll
        for (int x = 0; x < 32; x += 4) {
          float4 kv = *(const float4*)(Kr + x);
          pp += kv.x * XS[(kq << 5) + x] + kv.y * XS[(kq << 5) + x + 1] +
                kv.z * XS[(kq << 5) + x + 2] + kv.w * XS[(kq << 5) + x + 3];
        }
        XS[128 + (tl << 2) + kq] = pp;
      }
      __syncthreads();
      if (tid < 128) {
        float e = XS[128 + (tid << 2)] + XS[128 + (tid << 2) + 1] +
                  XS[128 + (tid << 2) + 2] + XS[128 + (tid << 2) + 3];
        bool ok = (t0 + tid) < len;
        XS[640 + tid] = e;                       // raw e
        XS[1536 + tid] = ok ? e : -3.0e38f;      // masked, for max
      }
      __syncthreads();
      for (int off = 64; off > 0; off >>= 1) {
        if (tid < off) XS[1536 + tid] = fmaxf(XS[1536 + tid], XS[1536 + tid + off]);
        __syncthreads();
      }
      const float mw = XS[1536];
      __syncthreads();
      if (tid < 128) {
        bool ok = (t0 + tid) < len;
        float ex = ok ? expf(XS[640 + tid] - mw) : 0.f;
        XS[768 + tid] = ex;
        XS[1536 + tid] = ex;
      }
      __syncthreads();
      for (int off = 64; off > 0; off >>= 1) {
        if (tid < off) XS[1536 + tid] += XS[1536 + tid + off];
        __syncthreads();
      }
      const float sw = XS[1536];
      if (tid == 0) {  // 4-wg mini-barrier: exchange (m,s), epoch-tagged flags
        unsigned long long pk =
            ((unsigned long long)__float_as_uint(mw) << 32) | (unsigned long long)__float_as_uint(sw);
        __hip_atomic_store(&MBV[(n << 2) + q], pk, __ATOMIC_RELAXED, __HIP_MEMORY_SCOPE_AGENT);
        __hip_atomic_store(&MBF[(n << 2) + q], s + 1, __ATOMIC_RELEASE, __HIP_MEMORY_SCOPE_AGENT);
        float ms[4], ss[4];
#pragma unroll
        for (int q2 = 0; q2 < 4; q2++) {
          if (q2 == q) { ms[q2] = mw; ss[q2] = sw; }
          else {
            // flag poll RELAXED: payload ordered by control dependency (no load speculation)
            while (__hip_atomic_load(&MBF[(n << 2) + q2], __ATOMIC_RELAXED,
                                     __HIP_MEMORY_SCOPE_AGENT) < s + 1)
              __builtin_amdgcn_s_sleep(2);
            unsigned long long p2 = __hip_atomic_load(&MBV[(n << 2) + q2], __ATOMIC_RELAXED,
                                                      __HIP_MEMORY_SCOPE_AGENT);
            ms[q2] = __uint_as_float((unsigned int)(p2 >> 32));
            ss[q2] = __uint_as_float((unsigned int)(p2 & 0xffffffffULL));
          }
        }
        float M = fmaxf(fmaxf(ms[0], ms[1]), fmaxf(ms[2], ms[3]));
        float S = ss[0] * expf(ms[0] - M) + ss[1] * expf(ms[1] - M) +
                  ss[2] * expf(ms[2] - M) + ss[3] * expf(ms[3] - M);
        XS[1792] = expf(mw - M) / S;  // scale: a = ex * exp(mw-M)/S
      }
      __syncthreads();
      const float scale = XS[1792];
      if (tid < 128) {
        float a = XS[768 + tid] * scale;
        XS[768 + tid] = a;
        attn[(long long)n * 50688 + (long long)s * 512 + t0 + tid] = a;
      }
      __syncthreads();
      {  // context partial: thread = (v, t-eighth of slice)
        const int v2 = tid & 127, th = tid >> 7;
        const float* Vb = encV + ((long long)n * 512 + t0 + (th << 5)) * 128 + v2;
        float pp = 0.f;
#pragma unroll 8
        for (int x = 0; x < 32; x++) pp = fmaf(XS[768 + (th << 5) + x], Vb[(long long)x * 128], pp);
        XS[896 + (v2 << 2) + th] = pp;
      }
      __syncthreads();
      if (tid < 128) {
        float cv = XS[896 + (tid << 2)] + XS[896 + (tid << 2) + 1] +
                   XS[896 + (tid << 2) + 2] + XS[896 + (tid << 2) + 3];
        atomicAdd(&XC[(tid << 6) + n], cv);  // accumulate ctx across the 4 t-slices (LLC-resident)
      }
    }
    gridbar(BAR, w, tid, ep);
  }
  // tail: ctx(98) -> K3 A-matrix
  if (w >= 64 && w < 128) {
    const int n = w - 64;
    if (tid < 128) {
      float val = llc_loadf(&XC[(tid << 6) + n]);
      h2c[((long long)(98 * 64 + n)) * 256 + 128 + tid] = (f16)val;
    }
  }
}

// ============================ launch ============================
extern "C" void kernel_launch(void* const* d_in, const int* in_sizes, int n_in,
                              void* d_out, int out_size, void* d_ws, size_t ws_size,
                              hipStream_t stream)
{
  (void)in_sizes; (void)n_in; (void)out_size; (void)ws_size;
  const float* encK = (const float*)d_in[0];
  const float* encV = (const float*)d_in[1];
  const int*   lens = (const int*)d_in[2];
  const int*   text = (const int*)d_in[3];
  const float* emb  = (const float*)d_in[4];
  const float* Wih1 = (const float*)d_in[5];
  const float* Whh1 = (const float*)d_in[6];
  const float* bih1 = (const float*)d_in[7];
  const float* bhh1 = (const float*)d_in[8];
  const float* Wih2 = (const float*)d_in[9];
  const float* Whh2 = (const float*)d_in[10];
  const float* bih2 = (const float*)d_in[11];
  const float* bhh2 = (const float*)d_in[12];
  const float* Wout = (const float*)d_in[13];
  const float* bout = (const float*)d_in[14];

  char* ws = (char*)d_ws;
  f16*   Gst    = (f16*)(ws + 0ULL);          // [99][2048][64] fp16
  f16*   A1     = (f16*)(ws + 25952256ULL);   // [6400][512] fp16
  f16*   Wst16  = (f16*)(ws + 32505856ULL);   // [2048][512] fp16
  f16*   Wout16 = (f16*)(ws + 34603008ULL);   // [32000][256] fp16
  f16*   h2c    = (f16*)(ws + 50987008ULL);   // [6400][256] fp16
  float* Wpack  = (float*)(ws + 54263808ULL); // [2048][640]
  float* Wpack2 = (float*)(ws + 59506688ULL); // [512][640]
  float* b1s    = (float*)(ws + 60817408ULL);
  float* b2s    = (float*)(ws + 60825600ULL);
  char*  st     = ws + 60827648ULL;           // zeroed state block
  float* XC  = (float*)(st + 0);        // [128][64] ctx (transposed)
  float* X1b = (float*)(st + 32768);    // 2x [512][64] h1 double-buffer
  float* X2b = (float*)(st + 294912);   // 2x [128][64] h2 double-buffer
  float* H2R = (float*)(st + 524288);   // [64][128] h2 row-major
  unsigned long long* MBV = (unsigned long long*)(st + 557056);
  int* MBF = (int*)(st + 559104);
  int* BAR = (int*)(st + 560128);

  float* pred = (float*)d_out;
  float* attn = pred + 202752000LL;

  hipMemsetAsync(st, 0, 592896, stream);
  hipMemsetAsync(h2c, 0, 3276800, stream);  // incl. pad rows 6336..6399 for K3
  k0_prep<<<4096, 256, 0, stream>>>(Wih1, Whh1, bih1, bhh1, Wih2, Whh2, bih2, bhh2,
                                    Wout, emb, text, Wpack, Wpack2, b1s, b2s, Wst16, Wout16, A1);
  gemm_f16<1><<<dim3(16, 50), 256, 0, stream>>>(A1, Wst16, b1s, nullptr, Gst, 512);
  k2_recur<<<256, 512, 0, stream>>>(Gst, Wpack, Wpack2, b2s, encK, encV, lens,
                                    XC, X1b, X2b, H2R, MBV, MBF, BAR, h2c, attn);
  gemm_f16<2><<<dim3(250, 50), 256, 0, stream>>>(h2c, Wout16, bout, pred, nullptr, 256);
}

// Round 4
// 5450.701 us; speedup vs baseline: 1.3632x; 1.3632x over previous
//
#include <hip/hip_runtime.h>
#include <stdint.h>

typedef _Float16 f16;
typedef _Float16 f16x8 __attribute__((ext_vector_type(8)));
typedef float f32x4 __attribute__((ext_vector_type(4)));

// ---------- LLC-coherent (L2-bypass) loads: system-scope sc0 sc1 ----------
// Reads execute at the Infinity Cache (coherence point), immune to stale per-XCD L2
// lines, and leave the L2's read-only working set (weights, encK/V) untouched.
__device__ __forceinline__ float llc_loadf(const float* p) {
  float r;
  asm volatile("global_load_dword %0, %1, off sc0 sc1\n\t"
               "s_waitcnt vmcnt(0)"
               : "=v"(r) : "v"(p) : "memory");
  return r;
}

__device__ __forceinline__ void llc_load4x5(const f32x4* p0, const f32x4* p1,
                                            const f32x4* p2, const f32x4* p3,
                                            const f32x4* p4, f32x4& a, f32x4& b,
                                            f32x4& c, f32x4& d, f32x4& e) {
  asm volatile("global_load_dwordx4 %0, %5, off sc0 sc1\n\t"
               "global_load_dwordx4 %1, %6, off sc0 sc1\n\t"
               "global_load_dwordx4 %2, %7, off sc0 sc1\n\t"
               "global_load_dwordx4 %3, %8, off sc0 sc1\n\t"
               "global_load_dwordx4 %4, %9, off sc0 sc1\n\t"
               "s_waitcnt vmcnt(0)"
               : "=&v"(a), "=&v"(b), "=&v"(c), "=&v"(d), "=&v"(e)
               : "v"(p0), "v"(p1), "v"(p2), "v"(p3), "v"(p4)
               : "memory");
}

// system-scope relaxed store: compiler emits sc0sc1 write-through to LLC; completion
// is drained by the per-wave vmcnt(0) that __syncthreads emits before s_barrier.
__device__ __forceinline__ void llc_storef(float* p, float v) {
  __hip_atomic_store(p, v, __ATOMIC_RELAXED, __HIP_MEMORY_SCOPE_SYSTEM);
}

// ============================ K0: prep / pack / gather ============================
__global__ __launch_bounds__(256) void k0_prep(
    const float* __restrict__ Wih1, const float* __restrict__ Whh1,
    const float* __restrict__ bih1, const float* __restrict__ bhh1,
    const float* __restrict__ Wih2, const float* __restrict__ Whh2,
    const float* __restrict__ bih2, const float* __restrict__ bhh2,
    const float* __restrict__ Wout, const float* __restrict__ emb,
    const int* __restrict__ text,
    float* __restrict__ Wpack, float* __restrict__ Wpack2,
    float* __restrict__ b1s, float* __restrict__ b2s,
    f16* __restrict__ Wst16, f16* __restrict__ Wout16, f16* __restrict__ A1)
{
  const long long TOT = 14158336LL;
  for (long long i = (long long)blockIdx.x * 256 + threadIdx.x; i < TOT;
       i += (long long)gridDim.x * 256) {
    long long x = i;
    if (x < 1310720) {  // Wpack[j][k]: k<128 -> Wih1 ctx cols, else Whh1
      int j = (int)(x / 640), k = (int)(x % 640);
      Wpack[x] = (k < 128) ? Wih1[(long long)j * 640 + 512 + k]
                           : Whh1[(long long)j * 512 + (k - 128)];
      continue;
    }
    x -= 1310720;
    if (x < 327680) {  // Wpack2[j2][k]: k<512 -> Wih2, else Whh2
      int j = (int)(x / 640), k = (int)(x % 640);
      Wpack2[x] = (k < 512) ? Wih2[(long long)j * 512 + k]
                            : Whh2[(long long)j * 128 + (k - 512)];
      continue;
    }
    x -= 327680;
    if (x < 1048576) {  // Wst16[j][k] = fp16(Wih1[j][k]) static cols
      int j = (int)(x >> 9), k = (int)(x & 511);
      Wst16[x] = (f16)Wih1[(long long)j * 640 + k];
      continue;
    }
    x -= 1048576;
    if (x < 8192000) { Wout16[x] = (f16)Wout[x]; continue; }
    x -= 8192000;
    if (x < 2560) {
      if (x < 2048) b1s[x] = bih1[x] + bhh1[x];
      else b2s[x - 2048] = bih2[x - 2048] + bhh2[x - 2048];
      continue;
    }
    x -= 2560;
    {  // A1[m][k] = fp16(embedding[text[n][s]][k]), m = s*64+n, pad rows -> token 0 (zero row)
      int m = (int)(x >> 9), k = (int)(x & 511);
      int tok = (m < 6336) ? text[(m & 63) * 100 + (m >> 6)] : 0;
      A1[x] = (f16)emb[(long long)tok * 512 + k];
    }
  }
}

// ============================ K1/K3: fp16 MFMA GEMM ============================
// C[m][n] = sum_k A[m][k]*B[n][k] + bias[n];  M=6400(pad, write m<6336), tiles 128x128, BK=64
// EPI==1: K1 -> Gst fp16 [s][j][nb];  EPI==2: K3 -> pred f32 [nb][s][j]
template <int EPI>
__global__ __launch_bounds__(256) void gemm_f16(
    const f16* __restrict__ A, const f16* __restrict__ B,
    const float* __restrict__ bias, float* __restrict__ oF, f16* __restrict__ oH, int Kdim)
{
  __shared__ __align__(16) f16 As[128][72];  // pad 64->72: 2-way max bank alias (free)
  __shared__ __align__(16) f16 Bs[128][72];
  const int tid = threadIdx.x, lane = tid & 63, wv = tid >> 6;
  const int m0 = blockIdx.y << 7, n0 = blockIdx.x << 7;
  f32x4 acc[2][8];
#pragma unroll
  for (int i = 0; i < 2; i++)
#pragma unroll
    for (int t = 0; t < 8; t++) acc[i][t] = (f32x4){0.f, 0.f, 0.f, 0.f};
  for (int kt = 0; kt < Kdim; kt += 64) {
    __syncthreads();
#pragma unroll
    for (int i = tid; i < 1024; i += 256) {  // 128 rows x 8 chunks of 8 f16
      int r = i >> 3, c = (i & 7) << 3;
      *(f16x8*)&As[r][c] = *(const f16x8*)&A[(long long)(m0 + r) * Kdim + kt + c];
      *(f16x8*)&Bs[r][c] = *(const f16x8*)&B[(long long)(n0 + r) * Kdim + kt + c];
    }
    __syncthreads();
#pragma unroll
    for (int ks = 0; ks < 2; ks++) {
      const int kc = (ks << 5) + ((lane >> 4) << 3);
      f16x8 a0 = *(const f16x8*)&As[(wv << 5) + (lane & 15)][kc];
      f16x8 a1 = *(const f16x8*)&As[(wv << 5) + 16 + (lane & 15)][kc];
#pragma unroll
      for (int nt = 0; nt < 8; nt++) {
        f16x8 b = *(const f16x8*)&Bs[(nt << 4) + (lane & 15)][kc];
        acc[0][nt] = __builtin_amdgcn_mfma_f32_16x16x32_f16(a0, b, acc[0][nt], 0, 0, 0);
        acc[1][nt] = __builtin_amdgcn_mfma_f32_16x16x32_f16(a1, b, acc[1][nt], 0, 0, 0);
      }
    }
  }
  const int rb = m0 + (wv << 5) + ((lane >> 4) << 2);  // D row = quad*4+r
  const int cb = lane & 15;                            // D col = lane&15
#pragma unroll
  for (int i = 0; i < 2; i++)
#pragma unroll
    for (int nt = 0; nt < 8; nt++) {
      const int j = n0 + (nt << 4) + cb;
#pragma unroll
      for (int r = 0; r < 4; r++) {
        int m = rb + (i << 4) + r;
        if (m < 6336) {
          int s = m >> 6, n = m & 63;
          float dv = acc[i][nt][r] + bias[j];
          if (EPI == 1) oH[((long long)s * 2048 + j) * 64 + n] = (f16)dv;
          else          oF[(long long)n * 3168000 + (long long)s * 32000 + j] = dv;
        }
      }
    }
}

// ============================ K2: persistent recurrent kernel ============================
// Coherence protocol (fence-free): ALL cross-wg mutable state moves through the LLC —
// producers use system-scope relaxed stores (sc0sc1 write-through), consumers use sc0sc1
// loads, XC accumulation is agent-scope atomicAdd (RMW at LLC). __syncthreads drains each
// wave's vmcnt before s_barrier, so tid0's barrier signal orders after all stores.
// => zero buffer_wbl2 / buffer_inv in the whole loop; L2 holds only read-only data
// (Wpack2, encK/V, Gst) and stays warm across all 99 steps.
__device__ __forceinline__ void gridbar(int* bar, int w, int tid, int& ep) {
  __syncthreads();
  if (tid == 0) {
    const int e = ++ep;
    const int g = w & 7;
    int a = atomicAdd(bar + (g << 8), 1);      // 8 counters, 1 KB apart, 32 wgs each
    if (a == e * 32 - 1) {
      int r = atomicAdd(bar + 2048, 1);        // root
      if (r == e * 8 - 1) {
#pragma unroll
        for (int f = 0; f < 8; f++)
          __hip_atomic_store(bar + 2304 + (f << 8), e, __ATOMIC_RELAXED,
                             __HIP_MEMORY_SCOPE_AGENT);
      }
    }
    while (__hip_atomic_load(bar + 2304 + (g << 8), __ATOMIC_RELAXED,
                             __HIP_MEMORY_SCOPE_AGENT) < e)
      __builtin_amdgcn_s_sleep(2);
  }
  __syncthreads();
}

__global__ __launch_bounds__(512) void k2_recur(
    const f16* __restrict__ Gst, const float* __restrict__ Wpack,
    const float* __restrict__ Wpack2, const float* __restrict__ b2s,
    const float* __restrict__ encK, const float* __restrict__ encV,
    const int* __restrict__ lens,
    float* __restrict__ XC, float* __restrict__ X1b, float* __restrict__ X2b,
    float* __restrict__ H2R,
    unsigned long long* __restrict__ MBV, int* __restrict__ MBF, int* __restrict__ BAR,
    f16* __restrict__ h2c, float* __restrict__ attn)
{
  __shared__ __align__(16) float XS[10240];  // 40 KB: X staging chunk / gate exchange / softmax scratch
  __shared__ __align__(16) float WL[5120];   // 20 KB: this wg's 8 Wpack rows, resident all 99 steps
  const int w = blockIdx.x, tid = threadIdx.x;
  const int lane = tid & 63, wvv = tid >> 6;
  int ep = 0;
  float c1v = 0.f, c2v = 0.f;  // LSTM cell state: wg-private -> registers

  // ---- pin this wg's LSTM1 weight rows in LDS (once) ----
  {
    const int g = wvv >> 1, d = 2 * w + (wvv & 1);
    const int j = (g << 9) + d;
    const float* wrow = Wpack + (long long)j * 640;
    for (int k = lane; k < 640; k += 64) WL[wvv * 640 + k] = wrow[k];
  }

  for (int s = 0; s < 99; s++) {
    const int p = s & 1;
    // ---------- phase A: LSTM1 (all 256 wgs; wg owns d-pair {2w,2w+1}, wave = one gate row) ----------
    {
      const int g = wvv >> 1, d = 2 * w + (wvv & 1);
      const int j = (g << 9) + d;
      float acc = (float)Gst[((long long)s * 2048 + j) * 64 + lane];
      const f32x4* xc4 = (const f32x4*)XC;
      const f32x4* x1p4 = (const f32x4*)(X1b + p * 32768);
      const int wbase = wvv * 640;
      for (int c = 0; c < 4; c++) {  // stage 160 k-rows at a time: [XC(128) | h1(512)]
        __syncthreads();
        {
          const f32x4* ps[5];
#pragma unroll
          for (int u = 0; u < 5; u++) {
            int i = tid + (u << 9);
            int fidx = 2560 * c + i;
            int r = fidx >> 4;
            ps[u] = (r < 128) ? (xc4 + fidx) : (x1p4 + (fidx - 2048));
          }
          f32x4 v0, v1, v2, v3, v4;
          llc_load4x5(ps[0], ps[1], ps[2], ps[3], ps[4], v0, v1, v2, v3, v4);
          ((f32x4*)XS)[tid]          = v0;
          ((f32x4*)XS)[tid + 512]    = v1;
          ((f32x4*)XS)[tid + 1024]   = v2;
          ((f32x4*)XS)[tid + 1536]   = v3;
          ((f32x4*)XS)[tid + 2048]   = v4;
        }
        __syncthreads();
        const float* wc = &WL[wbase + 160 * c];  // LDS broadcast read, zero global traffic
#pragma unroll 8
        for (int k = 0; k < 160; k++) acc = fmaf(XS[(k << 6) + lane], wc[k], acc);
      }
      __syncthreads();
      XS[(wvv << 6) + lane] = acc;  // gate exchange
      __syncthreads();
      if (tid < 128) {
        const int dd = tid >> 6, n = tid & 63, dl = 2 * w + dd;
        float gi = XS[(dd << 6) + n];
        float gf = XS[((2 + dd) << 6) + n];
        float gg = XS[((4 + dd) << 6) + n];
        float go = XS[((6 + dd) << 6) + n];
        float si = 1.f / (1.f + expf(-gi));
        float sf = 1.f / (1.f + expf(-gf));
        float so = 1.f / (1.f + expf(-go));
        float cn = sf * c1v + si * tanhf(gg);
        float h = so * tanhf(cn);
        c1v = cn;
        llc_storef(&(X1b + (p ^ 1) * 32768)[(dl << 6) + n], h);
      }
    }
    gridbar(BAR, w, tid, ep);
    // ---------- phase B: LSTM2 (wgs 0..63) + side tasks (wgs 64..127) ----------
    if (w < 64) {
      const int g = wvv >> 1, d2 = 2 * w + (wvv & 1);
      const int j2 = __builtin_amdgcn_readfirstlane((g << 7) + d2);
      float acc = b2s[j2];
      const float* wrow = Wpack2 + (long long)j2 * 640;
      const f32x4* x1n4 = (const f32x4*)(X1b + (p ^ 1) * 32768);
      const f32x4* x2p4 = (const f32x4*)(X2b + p * 8192);
      for (int c = 0; c < 4; c++) {  // k-rows: [h1new(512) | h2old(128)]
        __syncthreads();
        {
          const f32x4* ps[5];
#pragma unroll
          for (int u = 0; u < 5; u++) {
            int i = tid + (u << 9);
            int fidx = 2560 * c + i;
            int r = fidx >> 4;
            ps[u] = (r < 512) ? (x1n4 + fidx) : (x2p4 + (fidx - 8192));
          }
          f32x4 v0, v1, v2, v3, v4;
          llc_load4x5(ps[0], ps[1], ps[2], ps[3], ps[4], v0, v1, v2, v3, v4);
          ((f32x4*)XS)[tid]          = v0;
          ((f32x4*)XS)[tid + 512]    = v1;
          ((f32x4*)XS)[tid + 1024]   = v2;
          ((f32x4*)XS)[tid + 1536]   = v3;
          ((f32x4*)XS)[tid + 2048]   = v4;
        }
        __syncthreads();
        const float* wc = wrow + 160 * c;
#pragma unroll 8
        for (int k = 0; k < 160; k++) acc = fmaf(XS[(k << 6) + lane], wc[k], acc);
      }
      __syncthreads();
      XS[(wvv << 6) + lane] = acc;
      __syncthreads();
      if (tid < 128) {
        const int dd = tid >> 6, n = tid & 63, dl = 2 * w + dd;
        float gi = XS[(dd << 6) + n];
        float gf = XS[((2 + dd) << 6) + n];
        float gg = XS[((4 + dd) << 6) + n];
        float go = XS[((6 + dd) << 6) + n];
        float si = 1.f / (1.f + expf(-gi));
        float sf = 1.f / (1.f + expf(-gf));
        float so = 1.f / (1.f + expf(-go));
        float cn = sf * c2v + si * tanhf(gg);
        float h = so * tanhf(cn);
        c2v = cn;
        llc_storef(&(X2b + (p ^ 1) * 8192)[(dl << 6) + n], h);
        llc_storef(&H2R[(n << 7) + dl], h);
        h2c[((long long)(s * 64 + n)) * 256 + dl] = (f16)h;  // K3 A-matrix h2 part
      }
    } else if (w < 128) {
      // finalize ctx(s-1) into K3 A-matrix, then zero XC for this step's accumulation
      const int n = w - 64;
      if (tid < 128) {
        float val = llc_loadf(&XC[(tid << 6) + n]);
        if (s > 0) h2c[((long long)((s - 1) * 64 + n)) * 256 + 128 + tid] = (f16)val;
        llc_storef(&XC[(tid << 6) + n], 0.f);
      }
    }
    gridbar(BAR, w, tid, ep);
    // ---------- phase C: attention (4 wgs per batch, t-slice of 128 each) ----------
    {
      const int q = w >> 6, n = w & 63, t0 = q << 7;
      const int len = lens[n];
      if (tid < 128) XS[tid] = llc_loadf(&H2R[(n << 7) + tid]);  // h2
      __syncthreads();
      {  // energy partials: thread = (t_local, k-quarter)
        const int tl = tid >> 2, kq = tid & 3;
        const float* Kr = encK + ((long long)n * 512 + t0 + tl) * 128 + (kq << 5);
        float pp = 0.f;
#pragma unroll
        for (int x = 0; x < 32; x += 4) {
          float4 kv = *(const float4*)(Kr + x);
          pp += kv.x * XS[(kq << 5) + x] + kv.y * XS[(kq << 5) + x + 1] +
                kv.z * XS[(kq << 5) + x + 2] + kv.w * XS[(kq << 5) + x + 3];
        }
        XS[128 + (tl << 2) + kq] = pp;
      }
      __syncthreads();
      if (tid < 128) {
        float e = XS[128 + (tid << 2)] + XS[128 + (tid << 2) + 1] +
                  XS[128 + (tid << 2) + 2] + XS[128 + (tid << 2) + 3];
        bool ok = (t0 + tid) < len;
        XS[640 + tid] = e;                       // raw e
        XS[1536 + tid] = ok ? e : -3.0e38f;      // masked, for max
      }
      __syncthreads();
      for (int off = 64; off > 0; off >>= 1) {
        if (tid < off) XS[1536 + tid] = fmaxf(XS[1536 + tid], XS[1536 + tid + off]);
        __syncthreads();
      }
      const float mw = XS[1536];
      __syncthreads();
      if (tid < 128) {
        bool ok = (t0 + tid) < len;
        float ex = ok ? expf(XS[640 + tid] - mw) : 0.f;
        XS[768 + tid] = ex;
        XS[1536 + tid] = ex;
      }
      __syncthreads();
      for (int off = 64; off > 0; off >>= 1) {
        if (tid < off) XS[1536 + tid] += XS[1536 + tid + off];
        __syncthreads();
      }
      const float sw = XS[1536];
      if (tid == 0) {  // 4-wg mini-barrier: exchange (m,s), epoch-tagged flags
        unsigned long long pk =
            ((unsigned long long)__float_as_uint(mw) << 32) | (unsigned long long)__float_as_uint(sw);
        __hip_atomic_store(&MBV[(n << 2) + q], pk, __ATOMIC_RELAXED, __HIP_MEMORY_SCOPE_AGENT);
        asm volatile("s_waitcnt vmcnt(0)" ::: "memory");  // order MBV before MBF (no release fence)
        __hip_atomic_store(&MBF[(n << 2) + q], s + 1, __ATOMIC_RELAXED, __HIP_MEMORY_SCOPE_AGENT);
        float ms[4], ss[4];
#pragma unroll
        for (int q2 = 0; q2 < 4; q2++) {
          if (q2 == q) { ms[q2] = mw; ss[q2] = sw; }
          else {
            // flag poll RELAXED: payload ordered by control dependency (no load speculation)
            while (__hip_atomic_load(&MBF[(n << 2) + q2], __ATOMIC_RELAXED,
                                     __HIP_MEMORY_SCOPE_AGENT) < s + 1)
              __builtin_amdgcn_s_sleep(2);
            unsigned long long p2 = __hip_atomic_load(&MBV[(n << 2) + q2], __ATOMIC_RELAXED,
                                                      __HIP_MEMORY_SCOPE_AGENT);
            ms[q2] = __uint_as_float((unsigned int)(p2 >> 32));
            ss[q2] = __uint_as_float((unsigned int)(p2 & 0xffffffffULL));
          }
        }
        float M = fmaxf(fmaxf(ms[0], ms[1]), fmaxf(ms[2], ms[3]));
        float S = ss[0] * expf(ms[0] - M) + ss[1] * expf(ms[1] - M) +
                  ss[2] * expf(ms[2] - M) + ss[3] * expf(ms[3] - M);
        XS[1792] = expf(mw - M) / S;  // scale: a = ex * exp(mw-M)/S
      }
      __syncthreads();
      const float scale = XS[1792];
      if (tid < 128) {
        float a = XS[768 + tid] * scale;
        XS[768 + tid] = a;
        attn[(long long)n * 50688 + (long long)s * 512 + t0 + tid] = a;
      }
      __syncthreads();
      {  // context partial: thread = (v, t-eighth of slice)
        const int v2 = tid & 127, th = tid >> 7;
        const float* Vb = encV + ((long long)n * 512 + t0 + (th << 5)) * 128 + v2;
        float pp = 0.f;
#pragma unroll 8
        for (int x = 0; x < 32; x++) pp = fmaf(XS[768 + (th << 5) + x], Vb[(long long)x * 128], pp);
        XS[896 + (v2 << 2) + th] = pp;
      }
      __syncthreads();
      if (tid < 128) {
        float cv = XS[896 + (tid << 2)] + XS[896 + (tid << 2) + 1] +
                   XS[896 + (tid << 2) + 2] + XS[896 + (tid << 2) + 3];
        atomicAdd(&XC[(tid << 6) + n], cv);  // accumulate ctx across the 4 t-slices (LLC RMW)
      }
    }
    gridbar(BAR, w, tid, ep);
  }
  // tail: ctx(98) -> K3 A-matrix
  if (w >= 64 && w < 128) {
    const int n = w - 64;
    if (tid < 128) {
      float val = llc_loadf(&XC[(tid << 6) + n]);
      h2c[((long long)(98 * 64 + n)) * 256 + 128 + tid] = (f16)val;
    }
  }
}

// ============================ launch ============================
extern "C" void kernel_launch(void* const* d_in, const int* in_sizes, int n_in,
                              void* d_out, int out_size, void* d_ws, size_t ws_size,
                              hipStream_t stream)
{
  (void)in_sizes; (void)n_in; (void)out_size; (void)ws_size;
  const float* encK = (const float*)d_in[0];
  const float* encV = (const float*)d_in[1];
  const int*   lens = (const int*)d_in[2];
  const int*   text = (const int*)d_in[3];
  const float* emb  = (const float*)d_in[4];
  const float* Wih1 = (const float*)d_in[5];
  const float* Whh1 = (const float*)d_in[6];
  const float* bih1 = (const float*)d_in[7];
  const float* bhh1 = (const float*)d_in[8];
  const float* Wih2 = (const float*)d_in[9];
  const float* Whh2 = (const float*)d_in[10];
  const float* bih2 = (const float*)d_in[11];
  const float* bhh2 = (const float*)d_in[12];
  const float* Wout = (const float*)d_in[13];
  const float* bout = (const float*)d_in[14];

  char* ws = (char*)d_ws;
  f16*   Gst    = (f16*)(ws + 0ULL);          // [99][2048][64] fp16
  f16*   A1     = (f16*)(ws + 25952256ULL);   // [6400][512] fp16
  f16*   Wst16  = (f16*)(ws + 32505856ULL);   // [2048][512] fp16
  f16*   Wout16 = (f16*)(ws + 34603008ULL);   // [32000][256] fp16
  f16*   h2c    = (f16*)(ws + 50987008ULL);   // [6400][256] fp16
  float* Wpack  = (float*)(ws + 54263808ULL); // [2048][640]
  float* Wpack2 = (float*)(ws + 59506688ULL); // [512][640]
  float* b1s    = (float*)(ws + 60817408ULL);
  float* b2s    = (float*)(ws + 60825600ULL);
  char*  st     = ws + 60827648ULL;           // zeroed state block
  float* XC  = (float*)(st + 0);        // [128][64] ctx (transposed)
  float* X1b = (float*)(st + 32768);    // 2x [512][64] h1 double-buffer
  float* X2b = (float*)(st + 294912);   // 2x [128][64] h2 double-buffer
  float* H2R = (float*)(st + 524288);   // [64][128] h2 row-major
  unsigned long long* MBV = (unsigned long long*)(st + 557056);
  int* MBF = (int*)(st + 559104);
  int* BAR = (int*)(st + 560128);

  float* pred = (float*)d_out;
  float* attn = pred + 202752000LL;

  hipMemsetAsync(st, 0, 592896, stream);
  hipMemsetAsync(h2c, 0, 3276800, stream);  // incl. pad rows 6336..6399 for K3
  k0_prep<<<4096, 256, 0, stream>>>(Wih1, Whh1, bih1, bhh1, Wih2, Whh2, bih2, bhh2,
                                    Wout, emb, text, Wpack, Wpack2, b1s, b2s, Wst16, Wout16, A1);
  gemm_f16<1><<<dim3(16, 50), 256, 0, stream>>>(A1, Wst16, b1s, nullptr, Gst, 512);
  k2_recur<<<256, 512, 0, stream>>>(Gst, Wpack, Wpack2, b2s, encK, encV, lens,
                                    XC, X1b, X2b, H2R, MBV, MBF, BAR, h2c, attn);
  gemm_f16<2><<<dim3(250, 50), 256, 0, stream>>>(h2c, Wout16, bout, pred, nullptr, 256);
}